// Round 7
// baseline (149.768 us; speedup 1.0000x reference)
//
#include <hip/hip_runtime.h>
#include <cstdint>
#include <cstddef>

typedef float f32x4 __attribute__((ext_vector_type(4)));
typedef __bf16 bf16x8 __attribute__((ext_vector_type(8)));
typedef __bf16 bf16x2 __attribute__((ext_vector_type(2)));
typedef uint32_t u32x4 __attribute__((ext_vector_type(4)));

#define TSS 9216
#define KST 104   // attn LDS row stride (bf16)
#define XST 72    // proj X^T LDS row stride (bf16)
#define WST 72    // out_proj W-chunk row stride (bf16)
#define RSTD 68   // out_proj A-chunk row stride in DWORDS

__device__ __forceinline__ uint32_t pack2bf(float a, float b) {
  bf16x2 v = { (__bf16)a, (__bf16)b };   // native v_cvt_pk_bf16_f32 (RNE)
  return __builtin_bit_cast(uint32_t, v);
}

// ---------------- Kernel 0: W fp32 -> bf16 (L2-resident operand for proj) ----------------
__global__ __launch_bounds__(256, 8) void wcvt_kernel(
    const float* __restrict__ w, uint16_t* __restrict__ wbf)
{
  const int i = blockIdx.x * 256 + threadIdx.x;   // 24576 float4 = 1536*64 floats
  const float4 v = ((const float4*)w)[i];
  ((uint2*)wbf)[i] = uint2{pack2bf(v.x, v.y), pack2bf(v.z, v.w)};
}

// ---------------- Kernel 1: vqk[b][o][p] = sum_c W[o][c] X[b][c][p] + bias[o] ----------------
// Strip-persistent: block = (b, 32-wide p strip). X^T staged ONCE (4.6 KB LDS, 1 barrier);
// A-frags live in regs for the whole block. Wave w covers o in [384w, 384w+384), 24 o-tiles,
// B-frags (W rows) read straight from L2-hot bf16 W, pipelined 1 tile ahead.
// Bias folded into MFMA acc init (lane's entire acc shares o = lcol).
__global__ __launch_bounds__(256, 5) void proj_kernel(
    const float* __restrict__ x, const uint16_t* __restrict__ wbf,
    const float* __restrict__ b_vkq, uint16_t* __restrict__ vqk)
{
  __shared__ __align__(16) uint16_t Bt[32 * XST];  // X^T tile [p][c]

  const int t   = threadIdx.x;
  const int blk = blockIdx.x;        // 1152 = 4b * 288 nt
  const int nt  = blk % 288;
  const int b   = blk / 288;
  const int n0  = nt * 32;

  // stage X^T: x[b][c][n0+p] -> Bt[p][c]; instr = 2 c-rows x 128 B, each x byte read once
  {
    const float* __restrict__ xb = x + (size_t)b * 64 * TSS + n0;
    const int p  = t & 31;
    const int c0 = (t >> 5) * 8;
    float v[8];
    #pragma unroll
    for (int i = 0; i < 8; ++i) v[i] = xb[(size_t)(c0 + i) * TSS + p];
    *(uint4*)&Bt[p * XST + c0] =
      uint4{pack2bf(v[0], v[1]), pack2bf(v[2], v[3]),
            pack2bf(v[4], v[5]), pack2bf(v[6], v[7])};
  }
  __syncthreads();

  const int L    = t & 63;
  const int w    = t >> 6;
  const int lcol = L & 15;
  const int lq   = L >> 4;

  // A-frags (X^T rows p) — invariant across all 24 o-tiles
  bf16x8 af[2][2];
  #pragma unroll
  for (int tm = 0; tm < 2; ++tm)
    #pragma unroll
    for (int ks = 0; ks < 2; ++ks)
      af[tm][ks] = *(const bf16x8*)&Bt[(tm*16 + lcol) * XST + ks*32 + lq*8];

  const int obase = w * 384;
  bf16x8 bw[2][2];
  #pragma unroll
  for (int ks = 0; ks < 2; ++ks)
    bw[0][ks] = *(const bf16x8*)(wbf + (size_t)(obase + lcol) * 64 + ks*32 + lq*8);

  for (int ot = 0; ot < 24; ++ot) {
    const int buf = ot & 1;
    if (ot < 23) {
      const int on = obase + (ot + 1) * 16 + lcol;
      #pragma unroll
      for (int ks = 0; ks < 2; ++ks)
        bw[buf ^ 1][ks] = *(const bf16x8*)(wbf + (size_t)on * 64 + ks*32 + lq*8);
    }
    const int o = obase + ot * 16 + lcol;
    const float bias = b_vkq[o];
    f32x4 acc[2];
    acc[0] = f32x4{bias, bias, bias, bias};
    acc[1] = acc[0];
    #pragma unroll
    for (int tm = 0; tm < 2; ++tm)
      #pragma unroll
      for (int ks = 0; ks < 2; ++ks)
        acc[tm] = __builtin_amdgcn_mfma_f32_16x16x32_bf16(af[tm][ks], bw[buf][ks], acc[tm], 0, 0, 0);

    uint16_t* __restrict__ dst = vqk + (size_t)(b * 1536 + o) * TSS + n0;
    #pragma unroll
    for (int tm = 0; tm < 2; ++tm)
      *(uint2*)(dst + tm*16 + lq*4) =
        uint2{pack2bf(acc[tm][0], acc[tm][1]), pack2bf(acc[tm][2], acc[tm][3])};
  }
}

// ---------------- Kernel 2: per-(b,hc) attention, D[z][x] form (unchanged from R6) ----------
__global__ __launch_bounds__(384, 5) void attn_kernel(uint16_t* __restrict__ vqk)
{
  __shared__ __align__(16) uint16_t Ks[96 * KST];  // K; reused for P after scores
  __shared__ __align__(16) uint16_t Qs[96 * KST];

  const int t   = threadIdx.x;
  const int blk = blockIdx.x;
  const int b   = blk >> 9;
  const int hc  = blk & 511;
  const size_t pbase = (size_t)(b * 1536 + hc) * TSS;
  const uint16_t* __restrict__ vplane = vqk + pbase;
  const uint16_t* __restrict__ kplane = vqk + pbase + (size_t)1024 * TSS;
  const uint16_t* __restrict__ qplane = vqk + pbase + (size_t)512  * TSS;

  {
    const uint4* __restrict__ sk = (const uint4*)kplane;
    const uint4* __restrict__ sq = (const uint4*)qplane;
    #pragma unroll
    for (int i = 0; i < 3; ++i) {
      const int g   = t + i * 384;
      const int row = g / 12;
      const int off = (g - row * 12) * 8;
      *(uint4*)&Ks[row * KST + off] = sk[g];
      *(uint4*)&Qs[row * KST + off] = sq[g];
    }
  }

  const int L    = t & 63;
  const int w    = t / 64;
  const int lcol = L & 15;
  const int lq   = L >> 4;
  const int xrow = 16 * w + lcol;
  const float C  = 1.44269504088896f / 9216.0f;
  const f32x4 zero4 = {0.f, 0.f, 0.f, 0.f};

  bf16x8 bv[3];
  #pragma unroll
  for (int ks = 0; ks < 3; ++ks)
    bv[ks] = *(const bf16x8*)(vplane + (size_t)xrow * 96 + ks*32 + lq*8);

  __syncthreads();

  f32x4 sa[6];
  #pragma unroll
  for (int i = 0; i < 6; ++i) sa[i] = zero4;
  #pragma unroll
  for (int tz = 0; tz < 6; ++tz)
    #pragma unroll
    for (int ks = 0; ks < 3; ++ks) {
      const bf16x8 ak = *(const bf16x8*)&Ks[(tz*16 + lcol) * KST + ks*32 + lq*8];
      sa[tz] = __builtin_amdgcn_mfma_f32_16x16x32_bf16(ak, bv[ks], sa[tz], 0, 0, 0);
    }

  // |s/9216| <= 0.007 -> max-subtraction safely dropped
  float s = 0.f;
  #pragma unroll
  for (int tz = 0; tz < 6; ++tz)
    #pragma unroll
    for (int r = 0; r < 4; ++r)
      s += __builtin_exp2f(sa[tz][r] * C);
  s += __shfl_xor(s, 16, 64);
  s += __shfl_xor(s, 32, 64);
  const float inv = 1.0f / s;

  __syncthreads();   // all waves done reading Ks -> overwrite with P

  #pragma unroll
  for (int tz = 0; tz < 6; ++tz) {
    const float p0 = __builtin_exp2f(sa[tz][0] * C) * inv;
    const float p1 = __builtin_exp2f(sa[tz][1] * C) * inv;
    const float p2 = __builtin_exp2f(sa[tz][2] * C) * inv;
    const float p3 = __builtin_exp2f(sa[tz][3] * C) * inv;
    *(uint2*)&Ks[xrow * KST + tz*16 + lq*4] = uint2{pack2bf(p0, p1), pack2bf(p2, p3)};
  }

  bf16x8 bp[3];
  #pragma unroll
  for (int ks = 0; ks < 3; ++ks)
    bp[ks] = *(const bf16x8*)&Ks[xrow * KST + ks*32 + lq*8];
  f32x4 oa[6];
  #pragma unroll
  for (int i = 0; i < 6; ++i) oa[i] = zero4;
  #pragma unroll
  for (int tz = 0; tz < 6; ++tz)
    #pragma unroll
    for (int ks = 0; ks < 3; ++ks) {
      const bf16x8 aq = *(const bf16x8*)&Qs[(tz*16 + lcol) * KST + ks*32 + lq*8];
      oa[tz] = __builtin_amdgcn_mfma_f32_16x16x32_bf16(aq, bp[ks], oa[tz], 0, 0, 0);
    }

  uint16_t* __restrict__ dst = vqk + pbase;
  #pragma unroll
  for (int tz = 0; tz < 6; ++tz)
    *(uint2*)(dst + (size_t)xrow * 96 + tz*16 + lq*4) =
      uint2{pack2bf(oa[tz][0], oa[tz][1]), pack2bf(oa[tz][2], oa[tz][3])};
}

// ---------------- Kernel 3 (MFMA GEMM, unchanged from R6) ----------------
__global__ __launch_bounds__(256, 4) void out_proj_kernel(
    const uint16_t* __restrict__ attn, const float* __restrict__ w_out,
    const float* __restrict__ b_out, float* __restrict__ out)
{
  __shared__ __align__(16) uint32_t As2[2][32 * RSTD];
  __shared__ __align__(16) uint16_t Wl[2][64 * WST];

  const int t    = threadIdx.x;
  const int blk  = blockIdx.x;          // 576 = 4b * 144 nt
  const int nt   = blk % 144;
  const int b    = blk / 144;
  const int n0   = nt * 64;
  const int L    = t & 63;
  const int w    = t >> 6;
  const int lcol = L & 15;
  const int lq   = L >> 4;
  const int kp_g = t >> 4;
  const int seg  = t & 15;

  const uint16_t* __restrict__ ab = attn + (size_t)b * 1536 * TSS;

  uint2  pa[2][2];
  float4 pw[4];

  auto load_chunk = [&](int k0) {
    #pragma unroll
    for (int i = 0; i < 2; ++i) {
      const int kp = kp_g + i * 16;
      const int ke = k0 + 2*kp, ko = ke + 1;
      const int pe = ((ke & 7) << 6) | (ke >> 3);
      const int po = ((ko & 7) << 6) | (ko >> 3);
      pa[i][0] = *(const uint2*)(ab + (size_t)pe * TSS + n0 + seg * 4);
      pa[i][1] = *(const uint2*)(ab + (size_t)po * TSS + n0 + seg * 4);
    }
    #pragma unroll
    for (int i = 0; i < 4; ++i) {
      const int idx = t + i * 256;
      pw[i] = *(const float4*)(w_out + (size_t)(idx >> 4) * 512 + k0 + (idx & 15) * 4);
    }
  };

  auto store_chunk = [&](int buf) {
    #pragma unroll
    for (int i = 0; i < 2; ++i) {
      const int kp = kp_g + i * 16;
      const uint2 a = pa[i][0], bb = pa[i][1];
      uint4 d;
      d.x = (a.x & 0xffffu) | (bb.x << 16);
      d.y = (a.x >> 16)     | (bb.x & 0xffff0000u);
      d.z = (a.y & 0xffffu) | (bb.y << 16);
      d.w = (a.y >> 16)     | (bb.y & 0xffff0000u);
      *(uint4*)&As2[buf][kp * RSTD + seg * 4] = d;
    }
    #pragma unroll
    for (int i = 0; i < 4; ++i) {
      const int idx = t + i * 256;
      const float4 v = pw[i];
      *(uint2*)&Wl[buf][(idx >> 4) * WST + (idx & 15) * 4] =
        uint2{pack2bf(v.x, v.y), pack2bf(v.z, v.w)};
    }
  };

  f32x4 acc[4];
  const f32x4 zero4 = {0.f, 0.f, 0.f, 0.f};
  #pragma unroll
  for (int tm = 0; tm < 4; ++tm) acc[tm] = zero4;

  load_chunk(0);

  for (int c = 0; c < 8; ++c) {
    const int buf = c & 1;
    store_chunk(buf);
    if (c < 7) load_chunk((c + 1) * 64);
    __syncthreads();
    #pragma unroll
    for (int ks = 0; ks < 2; ++ks) {
      u32x4 bb;
      #pragma unroll
      for (int jj = 0; jj < 4; ++jj)
        bb[jj] = As2[buf][(ks*16 + lq*4 + jj) * RSTD + w*16 + lcol];
      const bf16x8 bfr = __builtin_bit_cast(bf16x8, bb);
      #pragma unroll
      for (int tm = 0; tm < 4; ++tm) {
        const bf16x8 af = *(const bf16x8*)&Wl[buf][(tm*16 + lcol) * WST + ks*32 + lq*8];
        acc[tm] = __builtin_amdgcn_mfma_f32_16x16x32_bf16(af, bfr, acc[tm], 0, 0, 0);
      }
    }
  }

  const int p = n0 + w*16 + lcol;
  #pragma unroll
  for (int tm = 0; tm < 4; ++tm)
    #pragma unroll
    for (int r = 0; r < 4; ++r) {
      const int o = tm*16 + lq*4 + r;
      out[(size_t)(b * 64 + o) * TSS + p] = acc[tm][r] + b_out[o];
    }
}

extern "C" void kernel_launch(void* const* d_in, const int* in_sizes, int n_in,
                              void* d_out, int out_size, void* d_ws, size_t ws_size,
                              hipStream_t stream) {
  const float* x     = (const float*)d_in[0];
  const float* w_vkq = (const float*)d_in[1];
  const float* b_vkq = (const float*)d_in[2];
  const float* w_out = (const float*)d_in[3];
  const float* b_out = (const float*)d_in[4];
  float* out = (float*)d_out;
  uint16_t* vqk = (uint16_t*)d_ws;                 // 4*1536*9216 bf16 = 113.2 MB
  uint16_t* wbf = vqk + (size_t)4*1536*TSS;        // +196 KB for bf16 W

  wcvt_kernel<<<dim3(96), dim3(256), 0, stream>>>(w_vkq, wbf);
  proj_kernel<<<dim3(1152), dim3(256), 0, stream>>>(x, wbf, b_vkq, vqk);
  attn_kernel<<<dim3(2048), dim3(384), 0, stream>>>(vqk);
  out_proj_kernel<<<dim3(576), dim3(256), 0, stream>>>(vqk, w_out, b_out, out);
}